// Round 10
// baseline (215.325 us; speedup 1.0000x reference)
//
#include <hip/hip_runtime.h>
#include <hip/hip_bf16.h>

#define BATCH   16384
#define NUM_IN  4096
#define NUM_OUT 1024
#define NNZ     262144
#define BN_EPS  1e-3f

typedef __attribute__((ext_vector_type(8)))  short short8;
typedef __attribute__((ext_vector_type(4)))  float f32x4;
typedef __attribute__((ext_vector_type(4)))  unsigned int u32x4;

typedef __attribute__((address_space(3))) void        lds_void_t;
typedef const __attribute__((address_space(1))) void  g_void_t;

__device__ inline unsigned short f2bf(float f) {
    unsigned int u = __builtin_bit_cast(unsigned int, f);
    u += 0x7fffu + ((u >> 16) & 1u);
    return (unsigned short)(u >> 16);
}

// ---------------- kernel 1: zero W_t (fp32, transposed [NUM_OUT][NUM_IN]) ----
__global__ void k_zero(f32x4* __restrict__ p) {
    p[(size_t)blockIdx.x * 256 + threadIdx.x] = f32x4{0.f, 0.f, 0.f, 0.f};
}

// ---------------- kernel 2: scatter-add sparse values into W_t --------------
__global__ void k_scatter(const float* __restrict__ v, const int* __restrict__ r,
                          const int* __restrict__ c, float* __restrict__ wtf) {
    int i = blockIdx.x * 256 + threadIdx.x;
    atomicAdd(&wtf[(size_t)c[i] * NUM_IN + r[i]], v[i]);
}

// ---------------- kernel 3: fold BN scale into W (bf16) + bias_out ----------
__global__ void k_wprep(const float* __restrict__ wtf, const float* __restrict__ gamma,
                        const float* __restrict__ beta, const float* __restrict__ mean,
                        const float* __restrict__ var, unsigned short* __restrict__ wtb,
                        float* __restrict__ bias) {
    const int n = blockIdx.x;
    const int t = threadIdx.x;
    float acc = 0.f;
    for (int k = t; k < NUM_IN; k += 256) {
        float w = wtf[(size_t)n * NUM_IN + k];
        float s = gamma[k] * rsqrtf(var[k] + BN_EPS);
        wtb[(size_t)n * NUM_IN + k] = f2bf(w * s);
        acc += (beta[k] - mean[k] * s) * w;
    }
    #pragma unroll
    for (int o = 32; o; o >>= 1) acc += __shfl_down(acc, o, 64);
    __shared__ float red[4];
    if ((t & 63) == 0) red[t >> 6] = acc;
    __syncthreads();
    if (t == 0) bias[n] = red[0] + red[1] + red[2] + red[3];
}

// ---------------- kernel 4: bf16 MFMA GEMM: out = x @ W'^T + bias -----------
// Identical data layout / lane maps / MFMA order as round 9 (0 bank conflicts,
// refpassed). ONLY change: staging spread 1 unit per phase (m201/m196 fine
// interleave):
//   ph0: vmcnt(0) [B(kt), 3-ph old] | load A-half0(kt+1) | rd kk0/ml0-3 | MFMA
//   ph1: load A-half1(kt+1) + B-DMA(kt+1) | rd kk0/ml4-7 | MFMA
//   ph2: vmcnt(8) [A-half0 landed]  | write A-half0 | rd kk1/ml0-3 | MFMA
//   ph3: vmcnt(4) [A-half1 landed; B stays in flight] | write A-half1 | ...
#define BM 256
#define BN 256
#define BK 64
#define NT (NUM_IN / BK)      /* 64 */
#define SLOT 65536            /* A 32 KB (bf16 frag-major) + B 32 KB */
#define BOFF 32768

__global__ __launch_bounds__(512, 2) void k_gemm(const float* __restrict__ x,
                                                 const unsigned short* __restrict__ wt,
                                                 const float* __restrict__ bias,
                                                 float* __restrict__ out) {
    __shared__ __align__(128) char lds[2 * SLOT];

    // XCD swizzle: 256 blocks (1/CU); XCD x gets 8 m-panels x all 4 n-tiles.
    const int bid = blockIdx.x;
    const int swz = (bid & 7) * 32 + (bid >> 3);
    const int m0 = (swz >> 2) * BM;
    const int n0 = (swz & 3) * BN;

    const int t    = threadIdx.x;
    const int lane = t & 63;
    const int wid  = t >> 6;
    const int wm   = wid >> 2;        // 0..1 -> 128-row strip
    const int wn   = wid & 3;         // 0..3 -> 64-col strip

    const char* xb = (const char*)x;
    const char* wb = (const char*)wt;

    // A-write map (R9, 0-conflict): kk=(t>>2)&1, mf=i*4+(t>>7),
    // lam=((t>>3)&15)|((t&3)<<4), lam'=lam^(t&7)
    const int awBase = ((t >> 2) & 1) * 16384 + (t >> 7) * 1024
                     + (((((t >> 3) & 15) | ((t & 3) << 4)) ^ (t & 7)) * 16);
    // A-read lane offsets per kk (R9)
    const int la0 = (lane ^ (lane >> 4)) * 16;
    const int la1 = (lane ^ ((lane >> 4) | 4)) * 16;
    // B-read (R9): col = wn*64+nf*16+(l&15); chunk = (kk*4+(l>>4)) ^ (l&7)
    const int bColB = (wn * 64 + (lane & 15)) * 128;
    const int bC0   = (((lane >> 4)    ) ^ (lane & 7)) * 16;
    const int bC1   = ((4 + (lane >> 4)) ^ (lane & 7)) * 16;

    f32x4 rc0[4], rc1[4];             // A halves in flight (static-indexed)
    auto loadA01 = [&](int kt) {      // rows 0..127: issues i=0,1
        #pragma unroll
        for (int i = 0; i < 2; ++i) {
            const char* p = xb + (size_t)(m0 + i * 64 + (t >> 3)) * (NUM_IN * 4)
                          + (size_t)kt * (BK * 4) + (t & 7) * 32;
            rc0[2 * i]     = *(const f32x4*)(p);
            rc0[2 * i + 1] = *(const f32x4*)(p + 16);
        }
    };
    auto loadA23 = [&](int kt) {      // rows 128..255: issues i=2,3
        #pragma unroll
        for (int i = 0; i < 2; ++i) {
            const char* p = xb + (size_t)(m0 + (i + 2) * 64 + (t >> 3)) * (NUM_IN * 4)
                          + (size_t)kt * (BK * 4) + (t & 7) * 32;
            rc1[2 * i]     = *(const f32x4*)(p);
            rc1[2 * i + 1] = *(const f32x4*)(p + 16);
        }
    };
    auto convWriteA01 = [&](int sl) {
        char* dst = lds + sl * SLOT + awBase;
        #pragma unroll
        for (int i = 0; i < 2; ++i) {
            const unsigned int* f0 = (const unsigned int*)&rc0[2 * i];
            const unsigned int* f1 = (const unsigned int*)&rc0[2 * i + 1];
            u32x4 w;
            w[0] = __builtin_amdgcn_perm(f0[1], f0[0], 0x07060302u);
            w[1] = __builtin_amdgcn_perm(f0[3], f0[2], 0x07060302u);
            w[2] = __builtin_amdgcn_perm(f1[1], f1[0], 0x07060302u);
            w[3] = __builtin_amdgcn_perm(f1[3], f1[2], 0x07060302u);
            *(u32x4*)(dst + i * 4096) = w;
        }
    };
    auto convWriteA23 = [&](int sl) {
        char* dst = lds + sl * SLOT + awBase;
        #pragma unroll
        for (int i = 0; i < 2; ++i) {
            const unsigned int* f0 = (const unsigned int*)&rc1[2 * i];
            const unsigned int* f1 = (const unsigned int*)&rc1[2 * i + 1];
            u32x4 w;
            w[0] = __builtin_amdgcn_perm(f0[1], f0[0], 0x07060302u);
            w[1] = __builtin_amdgcn_perm(f0[3], f0[2], 0x07060302u);
            w[2] = __builtin_amdgcn_perm(f1[1], f1[0], 0x07060302u);
            w[3] = __builtin_amdgcn_perm(f1[3], f1[2], 0x07060302u);
            *(u32x4*)(dst + (i + 2) * 4096) = w;
        }
    };
    auto stageB = [&](int kt, int sl) {   // 4x 8KB DMA (R9)
        #pragma unroll
        for (int i = 0; i < 4; ++i) {
            int col = i * 64 + (t >> 3);
            size_t src = (size_t)(n0 + col) * (NUM_IN * 2) + (size_t)kt * (BK * 2)
                       + (((t & 7) ^ ((t >> 3) & 7)) * 16);
            __builtin_amdgcn_global_load_lds((g_void_t*)(wb + src),
                (lds_void_t*)(lds + sl * SLOT + BOFF + i * 8192 + t * 16), 16, 0, 0);
        }
    };

    short8 af[4], bf0[4], bf1[4];
    auto readA4 = [&](const char* A, int kk, int mh) {
        const char* base = A + kk * 16384 + (wm * 8 + mh * 4) * 1024
                         + (kk ? la1 : la0);
        af[0] = *(const short8*)(base);
        af[1] = *(const short8*)(base + 1024);
        af[2] = *(const short8*)(base + 2048);
        af[3] = *(const short8*)(base + 3072);
    };
    auto readB4 = [&](const char* B, int co, short8* bf) {
        const char* base = B + bColB + co;
        bf[0] = *(const short8*)(base);
        bf[1] = *(const short8*)(base + 2048);
        bf[2] = *(const short8*)(base + 4096);
        bf[3] = *(const short8*)(base + 6144);
    };

    f32x4 acc[8][4] = {};
    auto mfma16 = [&](short8* bf, int mlb) {
        __builtin_amdgcn_s_setprio(1);
        #pragma unroll
        for (int mi = 0; mi < 4; ++mi)
            #pragma unroll
            for (int nf = 0; nf < 4; ++nf)
                acc[mlb + mi][nf] = __builtin_amdgcn_mfma_f32_16x16x32_bf16(
                    af[mi], bf[nf], acc[mlb + mi][nf], 0, 0, 0);
        __builtin_amdgcn_s_setprio(0);
    };

    // ---- prologue: tile 0. A loads first, then B DMA; drain A, write, bar ----
    loadA01(0); loadA23(0);                        // vm +8
    stageB(0, 0);                                  // vm +4
    asm volatile("s_waitcnt vmcnt(4)" ::: "memory");   // A(0) landed, B(0) flies
    convWriteA01(0); convWriteA23(0);
    asm volatile("s_waitcnt lgkmcnt(0)" ::: "memory");
    __builtin_amdgcn_s_barrier();

    #pragma unroll 1
    for (int kt = 0; kt < NT; ++kt) {
        const int s = kt & 1;
        const char* Ap = lds + s * SLOT;
        const char* Bp = Ap + BOFF;
        const bool st = (kt + 1) < NT;
        // ---- phase 0: (kk0, ml0-3) ----
        asm volatile("s_waitcnt vmcnt(0)" ::: "memory");   // B(kt) (3-ph old)
        if (st) loadA01(kt + 1);
        readB4(Bp, bC0, bf0);
        readA4(Ap, 0, 0);
        __builtin_amdgcn_s_barrier();
        asm volatile("s_waitcnt lgkmcnt(0)" ::: "memory");
        __builtin_amdgcn_sched_barrier(0);
        mfma16(bf0, 0);
        __builtin_amdgcn_s_barrier();
        // ---- phase 1: (kk0, ml4-7) ----
        if (st) { loadA23(kt + 1); stageB(kt + 1, s ^ 1); }
        readA4(Ap, 0, 1);
        __builtin_amdgcn_s_barrier();
        asm volatile("s_waitcnt lgkmcnt(0)" ::: "memory");
        __builtin_amdgcn_sched_barrier(0);
        mfma16(bf0, 4);
        __builtin_amdgcn_s_barrier();
        // ---- phase 2: (kk1, ml0-3) ----
        if (st) {
            asm volatile("s_waitcnt vmcnt(8)" ::: "memory");  // A-half0 landed
            convWriteA01(s ^ 1);
        }
        readB4(Bp, bC1, bf1);
        readA4(Ap, 1, 0);
        __builtin_amdgcn_s_barrier();
        asm volatile("s_waitcnt lgkmcnt(0)" ::: "memory");
        __builtin_amdgcn_sched_barrier(0);
        mfma16(bf1, 0);
        __builtin_amdgcn_s_barrier();
        // ---- phase 3: (kk1, ml4-7) ----
        if (st) {
            asm volatile("s_waitcnt vmcnt(4)" ::: "memory");  // A-half1 landed
            convWriteA23(s ^ 1);                              // B(kt+1) flies on
        }
        readA4(Ap, 1, 1);
        __builtin_amdgcn_s_barrier();
        asm volatile("s_waitcnt lgkmcnt(0)" ::: "memory");
        __builtin_amdgcn_sched_barrier(0);
        mfma16(bf1, 4);
        __builtin_amdgcn_s_barrier();
    }

    // epilogue: D frag mapping col=lane&15, row=(lane>>4)*4+r
    float bj[4];
    #pragma unroll
    for (int n = 0; n < 4; ++n) bj[n] = bias[n0 + wn * 64 + n * 16 + (lane & 15)];
    const int mb = m0 + wm * 128 + (lane >> 4) * 4;
    const int nb = n0 + wn * 64 + (lane & 15);
    #pragma unroll
    for (int ml = 0; ml < 8; ++ml)
        #pragma unroll
        for (int n = 0; n < 4; ++n)
            #pragma unroll
            for (int r = 0; r < 4; ++r)
                out[(size_t)(mb + ml * 16 + r) * NUM_OUT + (nb + n * 16)] =
                    acc[ml][n][r] + bj[n];
}

extern "C" void kernel_launch(void* const* d_in, const int* in_sizes, int n_in,
                              void* d_out, int out_size, void* d_ws, size_t ws_size,
                              hipStream_t stream) {
    const float* x     = (const float*)d_in[0];
    const float* spv   = (const float*)d_in[1];
    const float* gamma = (const float*)d_in[2];
    const float* beta  = (const float*)d_in[3];
    const float* mean  = (const float*)d_in[4];
    const float* var   = (const float*)d_in[5];
    const int*   rows  = (const int*)d_in[6];
    const int*   cols  = (const int*)d_in[7];
    float* out = (float*)d_out;

    // W_t fp32 scratch lives in d_out (dead before k_gemm overwrites it).
    float* wtf = (float*)d_out;
    unsigned short* wtb = (unsigned short*)d_ws;
    float* bias = (float*)((char*)d_ws + (size_t)NUM_IN * NUM_OUT * sizeof(unsigned short));

    hipLaunchKernelGGL(k_zero, dim3((NUM_IN * NUM_OUT / 4) / 256), dim3(256), 0, stream,
                       (f32x4*)wtf);
    hipLaunchKernelGGL(k_scatter, dim3(NNZ / 256), dim3(256), 0, stream,
                       spv, rows, cols, wtf);
    hipLaunchKernelGGL(k_wprep, dim3(NUM_OUT), dim3(256), 0, stream,
                       wtf, gamma, beta, mean, var, wtb, bias);
    hipLaunchKernelGGL(k_gemm, dim3((BATCH / BM) * (NUM_OUT / BN)), dim3(512), 0, stream,
                       x, wtb, bias, out);
}